// Round 10
// baseline (640.205 us; speedup 1.0000x reference)
//
#include <hip/hip_runtime.h>
#include <hip/hip_bf16.h>

#define THREADS 256
#define POOLS 16
#define BK2LOG 9
#define BK2SZ 512         // nodes per coarse bucket
#define EPT 16            // edges per thread in scatter
#define CHUNK (EPT * 256) // edges per scatter block

typedef __attribute__((ext_vector_type(8))) short bf16x8;
typedef __attribute__((ext_vector_type(4))) float f32x4;

static inline size_t align_up(size_t x, size_t a) { return (x + a - 1) & ~(a - 1); }

__device__ __forceinline__ float bf_lo(unsigned v) { return __uint_as_float(v << 16); }
__device__ __forceinline__ float bf_hi(unsigned v) { return __uint_as_float(v & 0xffff0000u); }

__device__ __forceinline__ void gl_lds16(const void* g, void* l) {
  __builtin_amdgcn_global_load_lds(
      (const __attribute__((address_space(1))) unsigned*)g,
      (__attribute__((address_space(3))) unsigned*)l, 16, 0, 0);
}

// ---------- detect whether index inputs are stored as int64 (low/high words) ----------
__global__ void k_detect(const int* __restrict__ ei, int* __restrict__ flag) {
  if (blockIdx.x == 0 && threadIdx.x == 0) {
    int odd_zero = ((ei[1] | ei[3] | ei[5] | ei[7]) == 0);
    int even_nz  = ((ei[0] | ei[2] | ei[4] | ei[6]) != 0);
    flag[0] = (odd_zero && even_nz) ? 1 : 0;
  }
}

// ---------- fused weight prep: Wp[layer][wc(8)][f(24)][lane(64)][j(8)] bf16 ----------
// f 0-7: r (ks<4 -> Wc, else Whh); f 8-15: z; f 16-19: i_n (Wc); f 20-23: h_n (Whh)
// Wc[layer][row][k] = sum_t weight[layer][k][t] * w_ih[row][t]  (computed inline)
__global__ void k_wcp(const float* __restrict__ weight, const float* __restrict__ w_ih,
                      const float* __restrict__ whh, __hip_bfloat16* __restrict__ Wp) {
  int idx = blockIdx.x * blockDim.x + threadIdx.x;
  const int per_layer = 8 * 24 * 64 * 8;  // 98304
  if (idx >= 3 * per_layer) return;
  int layer = idx / per_layer;
  int rem = idx % per_layer;
  int j    = rem & 7;
  int lane = (rem >> 3) & 63;
  int f    = (rem >> 9) % 24;
  int wc   = rem / (24 * 512);
  int col  = wc * 16 + (lane & 15);
  int kl   = (lane >> 4) * 8 + j;
  int gate, ks;
  bool from_wc;
  if (f < 8)       { gate = 0; ks = f;      from_wc = (ks < 4); }
  else if (f < 16) { gate = 1; ks = f - 8;  from_wc = (ks < 4); }
  else if (f < 20) { gate = 2; ks = f - 16; from_wc = true;  }
  else             { gate = 2; ks = f - 20; from_wc = false; }
  int row = gate * 128 + col;
  int k   = (ks & 3) * 32 + kl;
  float v;
  if (from_wc) {
    const float* wp = weight + (size_t)layer * 16384 + (size_t)k * 128;
    const float* ip = w_ih + (size_t)row * 128;
    float s = 0.f;
#pragma unroll 8
    for (int t = 0; t < 128; ++t) s += wp[t] * ip[t];
    v = s;
  } else {
    v = whh[(size_t)row * 128 + k];
  }
  Wp[idx] = __float2bfloat16(v);
}

// ---------- hb = bf16(x) ----------
__global__ void k_init(const float* __restrict__ x, __hip_bfloat16* __restrict__ hb,
                       int total4) {
  int i = blockIdx.x * blockDim.x + threadIdx.x;
  if (i >= total4) return;
  float4 v = ((const float4*)x)[i];
  __hip_bfloat162 a, b;
  a.x = __float2bfloat16(v.x); a.y = __float2bfloat16(v.y);
  b.x = __float2bfloat16(v.z); b.y = __float2bfloat16(v.w);
  ((__hip_bfloat162*)hb)[2 * i]     = a;
  ((__hip_bfloat162*)hb)[2 * i + 1] = b;
}

// ---------- two-level CSR build ----------
__global__ void k_bhist(const int* __restrict__ ei, int* __restrict__ bcount,
                        int E, int NB2, const int* __restrict__ flag) {
  __shared__ int lh[256];
  int t = threadIdx.x;
  lh[t] = 0;
  __syncthreads();
  int s64 = flag[0];
  int stride = gridDim.x * blockDim.x;
  for (int i = blockIdx.x * blockDim.x + t; i < E; i += stride) {
    size_t idx = s64 ? 2 * ((size_t)E + (size_t)i) : ((size_t)E + (size_t)i);
    atomicAdd(&lh[ei[idx] >> BK2LOG], 1);
  }
  __syncthreads();
  if (t < NB2 && lh[t]) atomicAdd(&bcount[t], lh[t]);
}

__global__ void k_bscan(const int* __restrict__ bcount, int* __restrict__ boffs,
                        int* __restrict__ bcursor, int NB2, int E) {
  __shared__ int s[256];
  int t = threadIdx.x;
  int v = (t < NB2) ? bcount[t] : 0;
  s[t] = v;
  __syncthreads();
  for (int d = 1; d < 256; d <<= 1) {
    int x = (t >= d) ? s[t - d] : 0;
    __syncthreads();
    s[t] += x;
    __syncthreads();
  }
  if (t < NB2) {
    int o = s[t] - v;
    boffs[t] = o;
    bcursor[t] = o;
  }
  if (t == 0) boffs[NB2] = E;
}

__global__ void k_bscatter(const int* __restrict__ ei, int* __restrict__ bcursor,
                           int* __restrict__ scratch, int E,
                           const int* __restrict__ flag) {
  __shared__ int lcnt[256];
  __shared__ int gbase[256];
  int t = threadIdx.x;
  lcnt[t] = 0;
  __syncthreads();
  int s64 = flag[0];
  int base = blockIdx.x * CHUNK;
  int pk[EPT], bk[EPT];
#pragma unroll
  for (int e = 0; e < EPT; ++e) {
    int i = base + e * 256 + t;
    if (i < E) {
      int sv = ei[s64 ? 2 * (size_t)i : (size_t)i];
      int dv = ei[s64 ? 2 * ((size_t)E + (size_t)i) : ((size_t)E + (size_t)i)];
      bk[e] = dv >> BK2LOG;
      pk[e] = (sv << BK2LOG) | (dv & (BK2SZ - 1));
      atomicAdd(&lcnt[bk[e]], 1);
    } else {
      bk[e] = -1;
    }
  }
  __syncthreads();
  int c = lcnt[t];
  if (c > 0) gbase[t] = atomicAdd(&bcursor[t], c);
  __syncthreads();
  lcnt[t] = 0;   // reuse as local cursor
  __syncthreads();
#pragma unroll
  for (int e = 0; e < EPT; ++e) {
    if (bk[e] >= 0) {
      int li = atomicAdd(&lcnt[bk[e]], 1);
      scratch[gbase[bk[e]] + li] = pk[e];
    }
  }
}

__global__ void k_bcsr(const int* __restrict__ scratch, const int* __restrict__ boffs,
                       int* __restrict__ offs, int* __restrict__ csr,
                       int n, int NB2, int E) {
  __shared__ int lcnt[BK2SZ];
  __shared__ int lcur[BK2SZ];
  int b = blockIdx.x, t = threadIdx.x;  // 256 threads
  int s = boffs[b], e = boffs[b + 1];
  lcnt[t] = 0;
  lcnt[t + 256] = 0;
  __syncthreads();
  for (int i = s + t; i < e; i += 256)
    atomicAdd(&lcnt[scratch[i] & (BK2SZ - 1)], 1);
  __syncthreads();
  if (t < 64) {
    int run = 0;
    for (int cch = 0; cch < 8; ++cch) {
      int idx = cch * 64 + t;
      int vv = lcnt[idx];
      int inc = vv;
#pragma unroll
      for (int d = 1; d < 64; d <<= 1) {
        int x = __shfl_up(inc, d);
        if (t >= d) inc += x;
      }
      lcur[idx] = run + inc - vv;
      run += __shfl(inc, 63);
    }
  }
  __syncthreads();
  for (int i = t; i < BK2SZ; i += 256) {
    int node = b * BK2SZ + i;
    if (node < n) offs[node] = s + lcur[i];
  }
  if (b == NB2 - 1 && t == 0) offs[n] = E;
  __syncthreads();
  for (int i = s + t; i < e; i += 256) {
    int v = scratch[i];
    int nl = v & (BK2SZ - 1);
    int pos = atomicAdd(&lcur[nl], 1);
    csr[s + pos] = v >> BK2LOG;
  }
}

__global__ void k_bounds(const int* __restrict__ batch, int* __restrict__ gs,
                         int* __restrict__ ge, int n, const int* __restrict__ flag) {
  int i = blockIdx.x * blockDim.x + threadIdx.x;
  if (i >= n) return;
  int s64 = flag[0];
  int b  = batch[s64 ? 2 * (size_t)i : (size_t)i];
  int bp = (i > 0)     ? batch[s64 ? 2 * (size_t)(i - 1) : (size_t)(i - 1)] : -1;
  int bn = (i < n - 1) ? batch[s64 ? 2 * (size_t)(i + 1) : (size_t)(i + 1)] : -1;
  if (i == 0 || bp != b) gs[b] = i;
  if (i == n - 1 || bn != b) ge[b] = i + 1;
}

// ---------- aggregation: agg[n] = sum over in-edges of hb[src]; 16-deep gather ----------
// (r8-proven version, reverted verbatim)
__global__ void k_agg(const __hip_bfloat16* __restrict__ hb, const int* __restrict__ offs,
                      const int* __restrict__ csr, __hip_bfloat16* __restrict__ agg, int n) {
  int node = (blockIdx.x * THREADS + threadIdx.x) >> 6;
  int lane = threadIdx.x & 63;
  if (node >= n) return;
  const unsigned* base = (const unsigned*)hb + lane;  // row stride = 64 uints
  int s = offs[node], e = offs[node + 1];
  float ax0 = 0.f, ay0 = 0.f, ax1 = 0.f, ay1 = 0.f;
  float ax2 = 0.f, ay2 = 0.f, ax3 = 0.f, ay3 = 0.f;
  for (int bs = s; bs < e; bs += 64) {
    int cnt = e - bs; if (cnt > 64) cnt = 64;
    int idx = csr[bs + ((lane < cnt) ? lane : (cnt - 1))];  // one coalesced load
    int j = 0;
    for (; j + 16 <= cnt; j += 16) {            // 16 loads in flight
      unsigned v[16];
#pragma unroll
      for (int q = 0; q < 16; ++q)
        v[q] = base[(size_t)__shfl(idx, j + q) * 64];
#pragma unroll
      for (int q = 0; q < 16; q += 4) {
        ax0 += bf_lo(v[q + 0]); ay0 += bf_hi(v[q + 0]);
        ax1 += bf_lo(v[q + 1]); ay1 += bf_hi(v[q + 1]);
        ax2 += bf_lo(v[q + 2]); ay2 += bf_hi(v[q + 2]);
        ax3 += bf_lo(v[q + 3]); ay3 += bf_hi(v[q + 3]);
      }
    }
    for (; j + 4 <= cnt; j += 4) {
      unsigned v0 = base[(size_t)__shfl(idx, j + 0) * 64];
      unsigned v1 = base[(size_t)__shfl(idx, j + 1) * 64];
      unsigned v2 = base[(size_t)__shfl(idx, j + 2) * 64];
      unsigned v3 = base[(size_t)__shfl(idx, j + 3) * 64];
      ax0 += bf_lo(v0); ay0 += bf_hi(v0);
      ax1 += bf_lo(v1); ay1 += bf_hi(v1);
      ax2 += bf_lo(v2); ay2 += bf_hi(v2);
      ax3 += bf_lo(v3); ay3 += bf_hi(v3);
    }
    for (; j < cnt; ++j) {
      unsigned v = base[(size_t)__shfl(idx, j) * 64];
      ax0 += bf_lo(v); ay0 += bf_hi(v);
    }
  }
  float ax = (ax0 + ax1) + (ax2 + ax3);
  float ay = (ay0 + ay1) + (ay2 + ay3);
  __hip_bfloat162 o;
  o.x = __float2bfloat16(ax);
  o.y = __float2bfloat16(ay);
  *(__hip_bfloat162*)(agg + (size_t)node * 128 + lane * 2) = o;
}

// ---------- persistent MFMA GRU: hb_out = GRUCell(agg, hb_in)  (ping-pong, race-free) ----------
// 256 threads = 4 waves; block owns (tile, col-half): 32 rows x 64 cols.
// grid = 1024 = exactly 4 blocks/CU, all co-resident. Halves mapped (t, t+512):
// 512 % 8 == 0 -> a tile's two halves land on the SAME XCD -> shared L2 for the
// duplicated stage reads and merged dirty lines for the half-row writes.
__launch_bounds__(256, 4)
__global__ void k_gru_pers(const __hip_bfloat16* __restrict__ agg,
                           const __hip_bfloat16* __restrict__ hin,
                           __hip_bfloat16* __restrict__ hout,
                           const __hip_bfloat16* __restrict__ Wp,  // layer slice
                           const float* __restrict__ b_ih,
                           const float* __restrict__ b_hh,
                           int n, int ntiles) {
  __shared__ __align__(16) __hip_bfloat16 sA[2][2][32 * 128];  // [dbuf][agg|h] 32KB
  const int t     = threadIdx.x;
  const int lane  = t & 63;
  const int wc    = t >> 6;                        // wave 0..3
  const int tstep = gridDim.x >> 1;                // 512
  const int half  = (blockIdx.x >= tstep) ? 1 : 0; // col half
  const int wf    = half * 4 + wc;                 // full col-tile id 0..7

  // ---- weights -> registers (once) ----
  bf16x8 w[24];
  {
    const bf16x8* wp = (const bf16x8*)Wp + (size_t)(wf * 24) * 64 + lane;
#pragma unroll
    for (int f = 0; f < 24; ++f) w[f] = wp[(size_t)f * 64];
  }
  // ---- per-lane biases ----
  const int col = half * 64 + wc * 16 + (lane & 15);
  const float br  = b_ih[col] + b_hh[col];
  const float bz  = b_ih[128 + col] + b_hh[128 + col];
  const float bin = b_ih[256 + col];
  const float bhn = b_hh[256 + col];

  auto stage = [&](int buf, int tileIdx) {
    const char* ga = (const char*)agg + (size_t)tileIdx * 8192;
    const char* gh = (const char*)hin + (size_t)tileIdx * 8192;
#pragma unroll
    for (int p = 0; p < 2; ++p) {
      int slot = p * 256 + t;
      int row  = slot >> 4;
      int sc   = (slot & 15) ^ (row & 7);
      int gb   = row * 256 + sc * 16;
      char* la = (char*)&sA[buf][0][0] + p * 4096 + wc * 1024;  // wave-uniform base
      char* lh = (char*)&sA[buf][1][0] + p * 4096 + wc * 1024;
      gl_lds16(ga + gb, la);
      gl_lds16(gh + gb, lh);
    }
  };

  int tile = blockIdx.x - half * tstep;
  if (tile < ntiles) stage(0, tile);
  int cur = 0;

  for (; tile < ntiles; tile += tstep) {
    __syncthreads();   // buf[cur] staged; prev iter's LDS reads done
    int nxt = tile + tstep;
    if (nxt < ntiles) stage(cur ^ 1, nxt);

    const char* cb = (const char*)&sA[cur][0][0];
    f32x4 ar[2], az[2], ain[2], ahn[2];
#pragma unroll
    for (int mt = 0; mt < 2; ++mt) {
      ar[mt] = (f32x4){0.f, 0.f, 0.f, 0.f};
      az[mt] = (f32x4){0.f, 0.f, 0.f, 0.f};
      ain[mt] = (f32x4){0.f, 0.f, 0.f, 0.f};
      ahn[mt] = (f32x4){0.f, 0.f, 0.f, 0.f};
    }

#pragma unroll
    for (int ks = 0; ks < 4; ++ks) {
      bf16x8 aa[2], ah[2];
#pragma unroll
      for (int mt = 0; mt < 2; ++mt) {
        int row = mt * 16 + (lane & 15);
        int ch  = (ks * 4 + (lane >> 4)) ^ (row & 7);
        aa[mt] = *(const bf16x8*)(cb + row * 256 + ch * 16);
        ah[mt] = *(const bf16x8*)(cb + 8192 + row * 256 + ch * 16);
      }
#pragma unroll
      for (int mt = 0; mt < 2; ++mt) {
        ar[mt]  = __builtin_amdgcn_mfma_f32_16x16x32_bf16(aa[mt], w[ks],      ar[mt], 0, 0, 0);
        ar[mt]  = __builtin_amdgcn_mfma_f32_16x16x32_bf16(ah[mt], w[4 + ks],  ar[mt], 0, 0, 0);
        az[mt]  = __builtin_amdgcn_mfma_f32_16x16x32_bf16(aa[mt], w[8 + ks],  az[mt], 0, 0, 0);
        az[mt]  = __builtin_amdgcn_mfma_f32_16x16x32_bf16(ah[mt], w[12 + ks], az[mt], 0, 0, 0);
        ain[mt] = __builtin_amdgcn_mfma_f32_16x16x32_bf16(aa[mt], w[16 + ks], ain[mt], 0, 0, 0);
        ahn[mt] = __builtin_amdgcn_mfma_f32_16x16x32_bf16(ah[mt], w[20 + ks], ahn[mt], 0, 0, 0);
      }
    }

    // epilogue: h' = (1-z)*tanh(in + r*hn) + z*h_old ; h_old from LDS h-tile
    const __hip_bfloat16* hbase = &sA[cur][1][0];
    int row0 = tile * 32;
#pragma unroll
    for (int mt = 0; mt < 2; ++mt) {
#pragma unroll
      for (int j = 0; j < 4; ++j) {
        int lr = mt * 16 + (lane >> 4) * 4 + j;
        int grow = row0 + lr;
        if (grow < n) {
          float r  = 1.f / (1.f + __expf(-(ar[mt][j] + br)));
          float z  = 1.f / (1.f + __expf(-(az[mt][j] + bz)));
          float pa = ain[mt][j] + bin + r * (ahn[mt][j] + bhn);
          float e2 = __expf(2.f * pa);
          float nn = 1.f - 2.f / (e2 + 1.f);   // tanh, branch-free
          int ch2 = (col >> 3) ^ (lr & 7);
          float hold = __bfloat162float(hbase[lr * 128 + ch2 * 8 + (col & 7)]);
          float o = (1.f - z) * nn + z * hold;
          hout[(size_t)grow * 128 + col] = __float2bfloat16(o);
        }
      }
    }
    cur ^= 1;
  }
}

// ---------- per-node 1/max(||h||,eps) over bf16 state ----------
__global__ void k_norm(const __hip_bfloat16* __restrict__ hb, float* __restrict__ rnorm,
                       int n) {
  int node = (blockIdx.x * THREADS + threadIdx.x) >> 6;
  int lane = threadIdx.x & 63;
  if (node >= n) return;
  unsigned v = ((const unsigned*)hb)[(size_t)node * 64 + lane];
  float a = bf_lo(v), b = bf_hi(v);
  float s = a * a + b * b;
#pragma unroll
  for (int d = 1; d < 64; d <<= 1) s += __shfl_xor(s, d);
  if (lane == 0) rnorm[node] = 1.f / fmaxf(sqrtf(s), 1e-12f);
}

// ---------- per-graph max/mean pool of relu(hb * rnorm), split POOLS ways ----------
__global__ void k_pool(const __hip_bfloat16* __restrict__ hb, const float* __restrict__ rnorm,
                       const int* __restrict__ gs, const int* __restrict__ ge,
                       float* __restrict__ featp) {
  int g = blockIdx.x, sp = blockIdx.y;
  int c = threadIdx.x;  // 128
  int s = gs[g], e = ge[g];
  int len = e - s;
  int chunk = (len + POOLS - 1) / POOLS;
  int ns = s + sp * chunk;
  int ne = ns + chunk; if (ne > e) ne = e;
  float mx = 0.f, sm = 0.f;
  for (int nd = ns; nd < ne; ++nd) {
    float v = __bfloat162float(hb[(size_t)nd * 128 + c]) * rnorm[nd];
    v = fmaxf(v, 0.f);
    mx = fmaxf(mx, v);
    sm += v;
  }
  featp[((size_t)g * POOLS + sp) * 256 + c]       = mx;
  featp[((size_t)g * POOLS + sp) * 256 + 128 + c] = sm;
}

// ---------- fused pool-combine + final linear ----------
__global__ void k_pool2f(const float* __restrict__ featp, const int* __restrict__ gs,
                         const int* __restrict__ ge, const float* __restrict__ lin_w,
                         const float* __restrict__ lin_b, float* __restrict__ out) {
  int g = blockIdx.x;
  int c = threadIdx.x;  // 256
  __shared__ float sf[256];
  float mx = 0.f, sm = 0.f;
  for (int sp = 0; sp < POOLS; ++sp) {
    float v = featp[((size_t)g * POOLS + sp) * 256 + c];
    mx = fmaxf(mx, v);
    sm += v;
  }
  float cnt = fmaxf((float)(ge[g] - gs[g]), 1.f);
  sf[c] = (c < 128) ? mx : (sm / cnt);
  __syncthreads();
  if (c < 10) {
    float s = lin_b[c];
    const float* w = lin_w + (size_t)c * 256;
#pragma unroll 8
    for (int k = 0; k < 256; ++k) s += sf[k] * w[k];
    out[(size_t)g * 10 + c] = s;
  }
}

extern "C" void kernel_launch(void* const* d_in, const int* in_sizes, int n_in,
                              void* d_out, int out_size, void* d_ws, size_t ws_size,
                              hipStream_t stream) {
  const float* x      = (const float*)d_in[0];
  const int*   ei     = (const int*)d_in[1];
  const int*   batch  = (const int*)d_in[2];
  const float* weight = (const float*)d_in[3];
  const float* w_ih   = (const float*)d_in[4];
  const float* w_hh   = (const float*)d_in[5];
  const float* b_ih   = (const float*)d_in[6];
  const float* b_hh   = (const float*)d_in[7];
  const float* lin_w  = (const float*)d_in[8];
  const float* lin_b  = (const float*)d_in[9];
  float* out = (float*)d_out;

  const int N = in_sizes[0] / 128;   // 100000
  const int E = in_sizes[1] / 2;     // 1600000
  const int G = out_size / 10;       // 64
  const int NB2 = (N + BK2SZ - 1) / BK2SZ;  // 196 coarse buckets
  const int WP_PER_LAYER = 8 * 24 * 64 * 8;  // 98304

  char* wsc = (char*)d_ws;
  size_t off = 0;
  auto take = [&](size_t bytes) -> void* {
    void* p = wsc + off;
    off = align_up(off + bytes, 256);
    return p;
  };
  __hip_bfloat16*  hb0    = (__hip_bfloat16*)take((size_t)N * 128 * 2);
  __hip_bfloat16*  hb1    = (__hip_bfloat16*)take((size_t)N * 128 * 2);
  __hip_bfloat16*  agg    = (__hip_bfloat16*)take((size_t)N * 128 * 2);
  __hip_bfloat16*  Wp     = (__hip_bfloat16*)take((size_t)3 * WP_PER_LAYER * 2);
  float*           rnorm  = (float*)take((size_t)N * 4);
  int*             offs   = (int*)take(((size_t)N + 1) * 4);
  int*             bcount = (int*)take(256 * 4);
  int*             boffs  = (int*)take(257 * 4);
  int*             bcursor= (int*)take(256 * 4);
  int*             csr    = (int*)take((size_t)E * 4);
  int*             gs     = (int*)take((size_t)G * 4);
  int*             ge     = (int*)take((size_t)G * 4);
  float*           featp  = (float*)take((size_t)G * POOLS * 256 * 4);
  int*             flag   = (int*)take(256);
  int*             scratch = (int*)agg;   // agg not live during CSR build
  (void)ws_size; (void)n_in;

  hipMemsetAsync(bcount, 0, 256 * 4, stream);
  hipMemsetAsync(gs, 0, (size_t)G * 4, stream);
  hipMemsetAsync(ge, 0, (size_t)G * 4, stream);

  k_detect<<<1, 64, 0, stream>>>(ei, flag);
  k_wcp<<<(3 * WP_PER_LAYER + THREADS - 1) / THREADS, THREADS, 0, stream>>>(
      weight, w_ih, w_hh, Wp);
  k_init<<<(N * 32 + THREADS - 1) / THREADS, THREADS, 0, stream>>>(x, hb0, N * 32);

  // two-level CSR build
  k_bhist<<<128, THREADS, 0, stream>>>(ei, bcount, E, NB2, flag);
  k_bscan<<<1, 256, 0, stream>>>(bcount, boffs, bcursor, NB2, E);
  k_bscatter<<<(E + CHUNK - 1) / CHUNK, THREADS, 0, stream>>>(ei, bcursor, scratch, E, flag);
  k_bcsr<<<NB2, THREADS, 0, stream>>>(scratch, boffs, offs, csr, N, NB2, E);
  k_bounds<<<(N + 255) / 256, 256, 0, stream>>>(batch, gs, ge, N, flag);

  const int ntiles = (N + 31) / 32;  // 3125
  __hip_bfloat16* hin = hb0;
  __hip_bfloat16* hout = hb1;
  for (int layer = 0; layer < 3; ++layer) {
    k_agg<<<(N + 3) / 4, THREADS, 0, stream>>>(hin, offs, csr, agg, N);
    k_gru_pers<<<1024, 256, 0, stream>>>(
        agg, hin, hout, Wp + (size_t)layer * WP_PER_LAYER, b_ih, b_hh, N, ntiles);
    __hip_bfloat16* tmp = hin; hin = hout; hout = tmp;
  }
  // final state is in hin after the swap

  k_norm<<<(N + 3) / 4, THREADS, 0, stream>>>(hin, rnorm, N);
  k_pool<<<dim3(G, POOLS), 128, 0, stream>>>(hin, rnorm, gs, ge, featp);
  k_pool2f<<<G, 256, 0, stream>>>(featp, gs, ge, lin_w, lin_b, out);
}

// Round 11
// 454.515 us; speedup vs baseline: 1.4085x; 1.4085x over previous
//
#include <hip/hip_runtime.h>
#include <hip/hip_bf16.h>

#define THREADS 256
#define POOLS 16
#define BK2LOG 9
#define BK2SZ 512         // nodes per coarse bucket
#define EPT 16            // edges per thread in scatter
#define CHUNK (EPT * 256) // edges per scatter block

typedef __attribute__((ext_vector_type(8))) short bf16x8;
typedef __attribute__((ext_vector_type(4))) float f32x4;

static inline size_t align_up(size_t x, size_t a) { return (x + a - 1) & ~(a - 1); }

__device__ __forceinline__ float bf_lo(unsigned v) { return __uint_as_float(v << 16); }
__device__ __forceinline__ float bf_hi(unsigned v) { return __uint_as_float(v & 0xffff0000u); }

__device__ __forceinline__ void gl_lds16(const void* g, void* l) {
  __builtin_amdgcn_global_load_lds(
      (const __attribute__((address_space(1))) unsigned*)g,
      (__attribute__((address_space(3))) unsigned*)l, 16, 0, 0);
}

// ---------- detect whether index inputs are stored as int64 (low/high words) ----------
__global__ void k_detect(const int* __restrict__ ei, int* __restrict__ flag) {
  if (blockIdx.x == 0 && threadIdx.x == 0) {
    int odd_zero = ((ei[1] | ei[3] | ei[5] | ei[7]) == 0);
    int even_nz  = ((ei[0] | ei[2] | ei[4] | ei[6]) != 0);
    flag[0] = (odd_zero && even_nz) ? 1 : 0;
  }
}

// ---------- fused weight prep: Wp[layer][wc(8)][f(24)][lane(64)][j(8)] bf16 ----------
// f 0-7: r (ks<4 -> Wc, else Whh); f 8-15: z; f 16-19: i_n (Wc); f 20-23: h_n (Whh)
// Wc[layer][row][k] = sum_t weight[layer][k][t] * w_ih[row][t]  (computed inline)
__global__ void k_wcp(const float* __restrict__ weight, const float* __restrict__ w_ih,
                      const float* __restrict__ whh, __hip_bfloat16* __restrict__ Wp) {
  int idx = blockIdx.x * blockDim.x + threadIdx.x;
  const int per_layer = 8 * 24 * 64 * 8;  // 98304
  if (idx >= 3 * per_layer) return;
  int layer = idx / per_layer;
  int rem = idx % per_layer;
  int j    = rem & 7;
  int lane = (rem >> 3) & 63;
  int f    = (rem >> 9) % 24;
  int wc   = rem / (24 * 512);
  int col  = wc * 16 + (lane & 15);
  int kl   = (lane >> 4) * 8 + j;
  int gate, ks;
  bool from_wc;
  if (f < 8)       { gate = 0; ks = f;      from_wc = (ks < 4); }
  else if (f < 16) { gate = 1; ks = f - 8;  from_wc = (ks < 4); }
  else if (f < 20) { gate = 2; ks = f - 16; from_wc = true;  }
  else             { gate = 2; ks = f - 20; from_wc = false; }
  int row = gate * 128 + col;
  int k   = (ks & 3) * 32 + kl;
  float v;
  if (from_wc) {
    const float* wp = weight + (size_t)layer * 16384 + (size_t)k * 128;
    const float* ip = w_ih + (size_t)row * 128;
    float s = 0.f;
#pragma unroll 8
    for (int t = 0; t < 128; ++t) s += wp[t] * ip[t];
    v = s;
  } else {
    v = whh[(size_t)row * 128 + k];
  }
  Wp[idx] = __float2bfloat16(v);
}

// ---------- hb = bf16(x) ----------
__global__ void k_init(const float* __restrict__ x, __hip_bfloat16* __restrict__ hb,
                       int total4) {
  int i = blockIdx.x * blockDim.x + threadIdx.x;
  if (i >= total4) return;
  float4 v = ((const float4*)x)[i];
  __hip_bfloat162 a, b;
  a.x = __float2bfloat16(v.x); a.y = __float2bfloat16(v.y);
  b.x = __float2bfloat16(v.z); b.y = __float2bfloat16(v.w);
  ((__hip_bfloat162*)hb)[2 * i]     = a;
  ((__hip_bfloat162*)hb)[2 * i + 1] = b;
}

// ---------- two-level CSR build ----------
__global__ void k_bhist(const int* __restrict__ ei, int* __restrict__ bcount,
                        int E, int NB2, const int* __restrict__ flag) {
  __shared__ int lh[256];
  int t = threadIdx.x;
  lh[t] = 0;
  __syncthreads();
  int s64 = flag[0];
  int stride = gridDim.x * blockDim.x;
  for (int i = blockIdx.x * blockDim.x + t; i < E; i += stride) {
    size_t idx = s64 ? 2 * ((size_t)E + (size_t)i) : ((size_t)E + (size_t)i);
    atomicAdd(&lh[ei[idx] >> BK2LOG], 1);
  }
  __syncthreads();
  if (t < NB2 && lh[t]) atomicAdd(&bcount[t], lh[t]);
}

__global__ void k_bscan(const int* __restrict__ bcount, int* __restrict__ boffs,
                        int* __restrict__ bcursor, int NB2, int E) {
  __shared__ int s[256];
  int t = threadIdx.x;
  int v = (t < NB2) ? bcount[t] : 0;
  s[t] = v;
  __syncthreads();
  for (int d = 1; d < 256; d <<= 1) {
    int x = (t >= d) ? s[t - d] : 0;
    __syncthreads();
    s[t] += x;
    __syncthreads();
  }
  if (t < NB2) {
    int o = s[t] - v;
    boffs[t] = o;
    bcursor[t] = o;
  }
  if (t == 0) boffs[NB2] = E;
}

__global__ void k_bscatter(const int* __restrict__ ei, int* __restrict__ bcursor,
                           int* __restrict__ scratch, int E,
                           const int* __restrict__ flag) {
  __shared__ int lcnt[256];
  __shared__ int gbase[256];
  int t = threadIdx.x;
  lcnt[t] = 0;
  __syncthreads();
  int s64 = flag[0];
  int base = blockIdx.x * CHUNK;
  int pk[EPT], bk[EPT];
#pragma unroll
  for (int e = 0; e < EPT; ++e) {
    int i = base + e * 256 + t;
    if (i < E) {
      int sv = ei[s64 ? 2 * (size_t)i : (size_t)i];
      int dv = ei[s64 ? 2 * ((size_t)E + (size_t)i) : ((size_t)E + (size_t)i)];
      bk[e] = dv >> BK2LOG;
      pk[e] = (sv << BK2LOG) | (dv & (BK2SZ - 1));
      atomicAdd(&lcnt[bk[e]], 1);
    } else {
      bk[e] = -1;
    }
  }
  __syncthreads();
  int c = lcnt[t];
  if (c > 0) gbase[t] = atomicAdd(&bcursor[t], c);
  __syncthreads();
  lcnt[t] = 0;   // reuse as local cursor
  __syncthreads();
#pragma unroll
  for (int e = 0; e < EPT; ++e) {
    if (bk[e] >= 0) {
      int li = atomicAdd(&lcnt[bk[e]], 1);
      scratch[gbase[bk[e]] + li] = pk[e];
    }
  }
}

__global__ void k_bcsr(const int* __restrict__ scratch, const int* __restrict__ boffs,
                       int* __restrict__ offs, int* __restrict__ csr,
                       int n, int NB2, int E) {
  __shared__ int lcnt[BK2SZ];
  __shared__ int lcur[BK2SZ];
  int b = blockIdx.x, t = threadIdx.x;  // 256 threads
  int s = boffs[b], e = boffs[b + 1];
  lcnt[t] = 0;
  lcnt[t + 256] = 0;
  __syncthreads();
  for (int i = s + t; i < e; i += 256)
    atomicAdd(&lcnt[scratch[i] & (BK2SZ - 1)], 1);
  __syncthreads();
  if (t < 64) {
    int run = 0;
    for (int cch = 0; cch < 8; ++cch) {
      int idx = cch * 64 + t;
      int vv = lcnt[idx];
      int inc = vv;
#pragma unroll
      for (int d = 1; d < 64; d <<= 1) {
        int x = __shfl_up(inc, d);
        if (t >= d) inc += x;
      }
      lcur[idx] = run + inc - vv;
      run += __shfl(inc, 63);
    }
  }
  __syncthreads();
  for (int i = t; i < BK2SZ; i += 256) {
    int node = b * BK2SZ + i;
    if (node < n) offs[node] = s + lcur[i];
  }
  if (b == NB2 - 1 && t == 0) offs[n] = E;
  __syncthreads();
  for (int i = s + t; i < e; i += 256) {
    int v = scratch[i];
    int nl = v & (BK2SZ - 1);
    int pos = atomicAdd(&lcur[nl], 1);
    csr[s + pos] = v >> BK2LOG;
  }
}

__global__ void k_bounds(const int* __restrict__ batch, int* __restrict__ gs,
                         int* __restrict__ ge, int n, const int* __restrict__ flag) {
  int i = blockIdx.x * blockDim.x + threadIdx.x;
  if (i >= n) return;
  int s64 = flag[0];
  int b  = batch[s64 ? 2 * (size_t)i : (size_t)i];
  int bp = (i > 0)     ? batch[s64 ? 2 * (size_t)(i - 1) : (size_t)(i - 1)] : -1;
  int bn = (i < n - 1) ? batch[s64 ? 2 * (size_t)(i + 1) : (size_t)(i + 1)] : -1;
  if (i == 0 || bp != b) gs[b] = i;
  if (i == n - 1 || bn != b) ge[b] = i + 1;
}

// ---------- aggregation: agg[n] = sum over in-edges of hb[src]; 16-deep gather ----------
// (r8-proven version)
__global__ void k_agg(const __hip_bfloat16* __restrict__ hb, const int* __restrict__ offs,
                      const int* __restrict__ csr, __hip_bfloat16* __restrict__ agg, int n) {
  int node = (blockIdx.x * THREADS + threadIdx.x) >> 6;
  int lane = threadIdx.x & 63;
  if (node >= n) return;
  const unsigned* base = (const unsigned*)hb + lane;  // row stride = 64 uints
  int s = offs[node], e = offs[node + 1];
  float ax0 = 0.f, ay0 = 0.f, ax1 = 0.f, ay1 = 0.f;
  float ax2 = 0.f, ay2 = 0.f, ax3 = 0.f, ay3 = 0.f;
  for (int bs = s; bs < e; bs += 64) {
    int cnt = e - bs; if (cnt > 64) cnt = 64;
    int idx = csr[bs + ((lane < cnt) ? lane : (cnt - 1))];  // one coalesced load
    int j = 0;
    for (; j + 16 <= cnt; j += 16) {            // 16 loads in flight
      unsigned v[16];
#pragma unroll
      for (int q = 0; q < 16; ++q)
        v[q] = base[(size_t)__shfl(idx, j + q) * 64];
#pragma unroll
      for (int q = 0; q < 16; q += 4) {
        ax0 += bf_lo(v[q + 0]); ay0 += bf_hi(v[q + 0]);
        ax1 += bf_lo(v[q + 1]); ay1 += bf_hi(v[q + 1]);
        ax2 += bf_lo(v[q + 2]); ay2 += bf_hi(v[q + 2]);
        ax3 += bf_lo(v[q + 3]); ay3 += bf_hi(v[q + 3]);
      }
    }
    for (; j + 4 <= cnt; j += 4) {
      unsigned v0 = base[(size_t)__shfl(idx, j + 0) * 64];
      unsigned v1 = base[(size_t)__shfl(idx, j + 1) * 64];
      unsigned v2 = base[(size_t)__shfl(idx, j + 2) * 64];
      unsigned v3 = base[(size_t)__shfl(idx, j + 3) * 64];
      ax0 += bf_lo(v0); ay0 += bf_hi(v0);
      ax1 += bf_lo(v1); ay1 += bf_hi(v1);
      ax2 += bf_lo(v2); ay2 += bf_hi(v2);
      ax3 += bf_lo(v3); ay3 += bf_hi(v3);
    }
    for (; j < cnt; ++j) {
      unsigned v = base[(size_t)__shfl(idx, j) * 64];
      ax0 += bf_lo(v); ay0 += bf_hi(v);
    }
  }
  float ax = (ax0 + ax1) + (ax2 + ax3);
  float ay = (ay0 + ay1) + (ay2 + ay3);
  __hip_bfloat162 o;
  o.x = __float2bfloat16(ax);
  o.y = __float2bfloat16(ay);
  *(__hip_bfloat162*)(agg + (size_t)node * 128 + lane * 2) = o;
}

// ---------- persistent MFMA GRU: hb_out = GRUCell(agg, hb_in)  (ping-pong, race-free) ----------
// r8-proven geometry: 256 threads = 4 waves; block owns (tile, col-half);
// grid = 512, 2 blocks/CU (register-capped: ~192 unified regs/lane -> 2 waves/SIMD max).
// Adjacent half-pairing (2t, 2t+1) keeps partners temporally aligned (r10 lesson:
// temporal alignment, not XCD arithmetic, makes the duplicated stage reads cheap).
__launch_bounds__(256, 2)
__global__ void k_gru_pers(const __hip_bfloat16* __restrict__ agg,
                           const __hip_bfloat16* __restrict__ hin,
                           __hip_bfloat16* __restrict__ hout,
                           const __hip_bfloat16* __restrict__ Wp,  // layer slice
                           const float* __restrict__ b_ih,
                           const float* __restrict__ b_hh,
                           int n, int ntiles) {
  __shared__ __align__(16) __hip_bfloat16 sA[2][2][32 * 128];  // [dbuf][agg|h] 32KB
  const int t    = threadIdx.x;
  const int lane = t & 63;
  const int wc   = t >> 6;                 // wave 0..3
  const int half = blockIdx.x & 1;         // col half (fixed per block)
  const int wf   = half * 4 + wc;          // full col-tile id 0..7

  // ---- weights -> registers (once) ----
  bf16x8 w[24];
  {
    const bf16x8* wp = (const bf16x8*)Wp + (size_t)(wf * 24) * 64 + lane;
#pragma unroll
    for (int f = 0; f < 24; ++f) w[f] = wp[(size_t)f * 64];
  }
  // ---- per-lane biases ----
  const int col = half * 64 + wc * 16 + (lane & 15);
  const float br  = b_ih[col] + b_hh[col];
  const float bz  = b_ih[128 + col] + b_hh[128 + col];
  const float bin = b_ih[256 + col];
  const float bhn = b_hh[256 + col];

  auto stage = [&](int buf, int tileIdx) {
    const char* ga = (const char*)agg + (size_t)tileIdx * 8192;
    const char* gh = (const char*)hin + (size_t)tileIdx * 8192;
#pragma unroll
    for (int p = 0; p < 2; ++p) {
      int slot = p * 256 + t;
      int row  = slot >> 4;
      int sc   = (slot & 15) ^ (row & 7);
      int gb   = row * 256 + sc * 16;
      char* la = (char*)&sA[buf][0][0] + p * 4096 + wc * 1024;  // wave-uniform base
      char* lh = (char*)&sA[buf][1][0] + p * 4096 + wc * 1024;
      gl_lds16(ga + gb, la);
      gl_lds16(gh + gb, lh);
    }
  };

  const int tstep = gridDim.x >> 1;
  int tile = blockIdx.x >> 1;
  if (tile < ntiles) stage(0, tile);
  int cur = 0;

  for (; tile < ntiles; tile += tstep) {
    __syncthreads();   // buf[cur] staged; prev iter's LDS reads done
    int nxt = tile + tstep;
    if (nxt < ntiles) stage(cur ^ 1, nxt);

    const char* cb = (const char*)&sA[cur][0][0];
    f32x4 ar[2], az[2], ain[2], ahn[2];
#pragma unroll
    for (int mt = 0; mt < 2; ++mt) {
      ar[mt] = (f32x4){0.f, 0.f, 0.f, 0.f};
      az[mt] = (f32x4){0.f, 0.f, 0.f, 0.f};
      ain[mt] = (f32x4){0.f, 0.f, 0.f, 0.f};
      ahn[mt] = (f32x4){0.f, 0.f, 0.f, 0.f};
    }

#pragma unroll
    for (int ks = 0; ks < 4; ++ks) {
      bf16x8 aa[2], ah[2];
#pragma unroll
      for (int mt = 0; mt < 2; ++mt) {
        int row = mt * 16 + (lane & 15);
        int ch  = (ks * 4 + (lane >> 4)) ^ (row & 7);
        aa[mt] = *(const bf16x8*)(cb + row * 256 + ch * 16);
        ah[mt] = *(const bf16x8*)(cb + 8192 + row * 256 + ch * 16);
      }
#pragma unroll
      for (int mt = 0; mt < 2; ++mt) {
        ar[mt]  = __builtin_amdgcn_mfma_f32_16x16x32_bf16(aa[mt], w[ks],      ar[mt], 0, 0, 0);
        ar[mt]  = __builtin_amdgcn_mfma_f32_16x16x32_bf16(ah[mt], w[4 + ks],  ar[mt], 0, 0, 0);
        az[mt]  = __builtin_amdgcn_mfma_f32_16x16x32_bf16(aa[mt], w[8 + ks],  az[mt], 0, 0, 0);
        az[mt]  = __builtin_amdgcn_mfma_f32_16x16x32_bf16(ah[mt], w[12 + ks], az[mt], 0, 0, 0);
        ain[mt] = __builtin_amdgcn_mfma_f32_16x16x32_bf16(aa[mt], w[16 + ks], ain[mt], 0, 0, 0);
        ahn[mt] = __builtin_amdgcn_mfma_f32_16x16x32_bf16(ah[mt], w[20 + ks], ahn[mt], 0, 0, 0);
      }
    }

    // epilogue: h' = (1-z)*tanh(in + r*hn) + z*h_old ; h_old from LDS h-tile
    const __hip_bfloat16* hbase = &sA[cur][1][0];
    int row0 = tile * 32;
#pragma unroll
    for (int mt = 0; mt < 2; ++mt) {
#pragma unroll
      for (int j = 0; j < 4; ++j) {
        int lr = mt * 16 + (lane >> 4) * 4 + j;
        int grow = row0 + lr;
        if (grow < n) {
          float r  = 1.f / (1.f + __expf(-(ar[mt][j] + br)));
          float z  = 1.f / (1.f + __expf(-(az[mt][j] + bz)));
          float pa = ain[mt][j] + bin + r * (ahn[mt][j] + bhn);
          float e2 = __expf(2.f * pa);
          float nn = 1.f - 2.f / (e2 + 1.f);   // tanh, branch-free
          int ch2 = (col >> 3) ^ (lr & 7);
          float hold = __bfloat162float(hbase[lr * 128 + ch2 * 8 + (col & 7)]);
          float o = (1.f - z) * nn + z * hold;
          hout[(size_t)grow * 128 + col] = __float2bfloat16(o);
        }
      }
    }
    cur ^= 1;
  }
}

// ---------- per-node 1/max(||h||,eps) over bf16 state ----------
__global__ void k_norm(const __hip_bfloat16* __restrict__ hb, float* __restrict__ rnorm,
                       int n) {
  int node = (blockIdx.x * THREADS + threadIdx.x) >> 6;
  int lane = threadIdx.x & 63;
  if (node >= n) return;
  unsigned v = ((const unsigned*)hb)[(size_t)node * 64 + lane];
  float a = bf_lo(v), b = bf_hi(v);
  float s = a * a + b * b;
#pragma unroll
  for (int d = 1; d < 64; d <<= 1) s += __shfl_xor(s, d);
  if (lane == 0) rnorm[node] = 1.f / fmaxf(sqrtf(s), 1e-12f);
}

// ---------- per-graph max/mean pool of relu(hb * rnorm), split POOLS ways ----------
__global__ void k_pool(const __hip_bfloat16* __restrict__ hb, const float* __restrict__ rnorm,
                       const int* __restrict__ gs, const int* __restrict__ ge,
                       float* __restrict__ featp) {
  int g = blockIdx.x, sp = blockIdx.y;
  int c = threadIdx.x;  // 128
  int s = gs[g], e = ge[g];
  int len = e - s;
  int chunk = (len + POOLS - 1) / POOLS;
  int ns = s + sp * chunk;
  int ne = ns + chunk; if (ne > e) ne = e;
  float mx = 0.f, sm = 0.f;
  for (int nd = ns; nd < ne; ++nd) {
    float v = __bfloat162float(hb[(size_t)nd * 128 + c]) * rnorm[nd];
    v = fmaxf(v, 0.f);
    mx = fmaxf(mx, v);
    sm += v;
  }
  featp[((size_t)g * POOLS + sp) * 256 + c]       = mx;
  featp[((size_t)g * POOLS + sp) * 256 + 128 + c] = sm;
}

// ---------- fused pool-combine + final linear ----------
__global__ void k_pool2f(const float* __restrict__ featp, const int* __restrict__ gs,
                         const int* __restrict__ ge, const float* __restrict__ lin_w,
                         const float* __restrict__ lin_b, float* __restrict__ out) {
  int g = blockIdx.x;
  int c = threadIdx.x;  // 256
  __shared__ float sf[256];
  float mx = 0.f, sm = 0.f;
  for (int sp = 0; sp < POOLS; ++sp) {
    float v = featp[((size_t)g * POOLS + sp) * 256 + c];
    mx = fmaxf(mx, v);
    sm += v;
  }
  float cnt = fmaxf((float)(ge[g] - gs[g]), 1.f);
  sf[c] = (c < 128) ? mx : (sm / cnt);
  __syncthreads();
  if (c < 10) {
    float s = lin_b[c];
    const float* w = lin_w + (size_t)c * 256;
#pragma unroll 8
    for (int k = 0; k < 256; ++k) s += sf[k] * w[k];
    out[(size_t)g * 10 + c] = s;
  }
}

extern "C" void kernel_launch(void* const* d_in, const int* in_sizes, int n_in,
                              void* d_out, int out_size, void* d_ws, size_t ws_size,
                              hipStream_t stream) {
  const float* x      = (const float*)d_in[0];
  const int*   ei     = (const int*)d_in[1];
  const int*   batch  = (const int*)d_in[2];
  const float* weight = (const float*)d_in[3];
  const float* w_ih   = (const float*)d_in[4];
  const float* w_hh   = (const float*)d_in[5];
  const float* b_ih   = (const float*)d_in[6];
  const float* b_hh   = (const float*)d_in[7];
  const float* lin_w  = (const float*)d_in[8];
  const float* lin_b  = (const float*)d_in[9];
  float* out = (float*)d_out;

  const int N = in_sizes[0] / 128;   // 100000
  const int E = in_sizes[1] / 2;     // 1600000
  const int G = out_size / 10;       // 64
  const int NB2 = (N + BK2SZ - 1) / BK2SZ;  // 196 coarse buckets
  const int WP_PER_LAYER = 8 * 24 * 64 * 8;  // 98304

  char* wsc = (char*)d_ws;
  size_t off = 0;
  auto take = [&](size_t bytes) -> void* {
    void* p = wsc + off;
    off = align_up(off + bytes, 256);
    return p;
  };
  __hip_bfloat16*  hb0    = (__hip_bfloat16*)take((size_t)N * 128 * 2);
  __hip_bfloat16*  hb1    = (__hip_bfloat16*)take((size_t)N * 128 * 2);
  __hip_bfloat16*  agg    = (__hip_bfloat16*)take((size_t)N * 128 * 2);
  __hip_bfloat16*  Wp     = (__hip_bfloat16*)take((size_t)3 * WP_PER_LAYER * 2);
  float*           rnorm  = (float*)take((size_t)N * 4);
  int*             offs   = (int*)take(((size_t)N + 1) * 4);
  int*             bcount = (int*)take(256 * 4);
  int*             boffs  = (int*)take(257 * 4);
  int*             bcursor= (int*)take(256 * 4);
  int*             csr    = (int*)take((size_t)E * 4);
  int*             gs     = (int*)take((size_t)G * 4);
  int*             ge     = (int*)take((size_t)G * 4);
  float*           featp  = (float*)take((size_t)G * POOLS * 256 * 4);
  int*             flag   = (int*)take(256);
  int*             scratch = (int*)agg;   // agg not live during CSR build
  (void)ws_size; (void)n_in;

  hipMemsetAsync(bcount, 0, 256 * 4, stream);
  hipMemsetAsync(gs, 0, (size_t)G * 4, stream);
  hipMemsetAsync(ge, 0, (size_t)G * 4, stream);

  k_detect<<<1, 64, 0, stream>>>(ei, flag);
  k_wcp<<<(3 * WP_PER_LAYER + THREADS - 1) / THREADS, THREADS, 0, stream>>>(
      weight, w_ih, w_hh, Wp);
  k_init<<<(N * 32 + THREADS - 1) / THREADS, THREADS, 0, stream>>>(x, hb0, N * 32);

  // two-level CSR build
  k_bhist<<<128, THREADS, 0, stream>>>(ei, bcount, E, NB2, flag);
  k_bscan<<<1, 256, 0, stream>>>(bcount, boffs, bcursor, NB2, E);
  k_bscatter<<<(E + CHUNK - 1) / CHUNK, THREADS, 0, stream>>>(ei, bcursor, scratch, E, flag);
  k_bcsr<<<NB2, THREADS, 0, stream>>>(scratch, boffs, offs, csr, N, NB2, E);
  k_bounds<<<(N + 255) / 256, 256, 0, stream>>>(batch, gs, ge, N, flag);

  const int ntiles = (N + 31) / 32;  // 3125
  __hip_bfloat16* hin = hb0;
  __hip_bfloat16* hout = hb1;
  for (int layer = 0; layer < 3; ++layer) {
    k_agg<<<(N + 3) / 4, THREADS, 0, stream>>>(hin, offs, csr, agg, N);
    k_gru_pers<<<512, 256, 0, stream>>>(
        agg, hin, hout, Wp + (size_t)layer * WP_PER_LAYER, b_ih, b_hh, N, ntiles);
    __hip_bfloat16* tmp = hin; hin = hout; hout = tmp;
  }
  // final state is in hin after the swap

  k_norm<<<(N + 3) / 4, THREADS, 0, stream>>>(hin, rnorm, N);
  k_pool<<<dim3(G, POOLS), 128, 0, stream>>>(hin, rnorm, gs, ge, featp);
  k_pool2f<<<G, 256, 0, stream>>>(featp, gs, ge, lin_w, lin_b, out);
}